// Round 1
// baseline (147.889 us; speedup 1.0000x reference)
//
#include <hip/hip_runtime.h>
#include <hip/hip_bf16.h>

using ushort = unsigned short;

typedef __attribute__((ext_vector_type(8))) short bf16x8;
typedef __attribute__((ext_vector_type(4))) float f32x4;
typedef __attribute__((ext_vector_type(4))) unsigned short u16x4;

#define DEVINL __device__ __forceinline__

// ---- problem constants ----
// B=2, S=2048, D=1024, H=16, dk=64, M=B*S=4096
static constexpr int S_LEN = 2048;
static constexpr int DMODEL = 1024;

// workspace layout (ushort element offsets)
static constexpr size_t XQ_O = 0;              // 4M elems (bf16 of query_tensor) -- reused as CTX later
static constexpr size_t XK_O = 4194304;
static constexpr size_t XV_O = 8388608;
static constexpr size_t WQ_O = 12582912;       // 1M each
static constexpr size_t WK_O = 13631488;
static constexpr size_t WV_O = 14680064;
static constexpr size_t WO_O = 15728640;
static constexpr size_t QB_O = 16777216;       // Q [b][h][s][64]   4M
static constexpr size_t KB_O = 20971520;       // K [b][h][s][64]   4M
static constexpr size_t VT_O = 25165824;       // V^T [b][h][64][s] 4M
static constexpr size_t CTX_O = 0;             // ctx [b][s][1024] reuses XQ

DEVINL ushort f2bf(float f) {
  unsigned u = __builtin_bit_cast(unsigned, f);
  u += 0x7fffu + ((u >> 16) & 1u);   // RNE
  return (ushort)(u >> 16);
}

// ---------------- fp32 -> bf16 conversion of all inputs ----------------
__global__ __launch_bounds__(256) void cvt_all(
    const float* __restrict__ xq, const float* __restrict__ xk, const float* __restrict__ xv,
    const float* __restrict__ wq, const float* __restrict__ wk, const float* __restrict__ wv,
    const float* __restrict__ wo, ushort* __restrict__ ws)
{
  int e = (blockIdx.x * 256 + threadIdx.x) * 8;   // 16M elems total
  const float* s;
  if      (e < 4194304)  s = xq + e;
  else if (e < 8388608)  s = xk + (e - 4194304);
  else if (e < 12582912) s = xv + (e - 8388608);
  else if (e < 13631488) s = wq + (e - 12582912);
  else if (e < 14680064) s = wk + (e - 13631488);
  else if (e < 15728640) s = wv + (e - 14680064);
  else                   s = wo + (e - 15728640);
  float4 a = *(const float4*)s;
  float4 b = *(const float4*)(s + 4);
  union { u16x4 v; ushort u[4]; } r0, r1;
  r0.u[0] = f2bf(a.x); r0.u[1] = f2bf(a.y); r0.u[2] = f2bf(a.z); r0.u[3] = f2bf(a.w);
  r1.u[0] = f2bf(b.x); r1.u[1] = f2bf(b.y); r1.u[2] = f2bf(b.z); r1.u[3] = f2bf(b.w);
  *(u16x4*)(ws + e) = r0.v;
  *(u16x4*)(ws + e + 4) = r1.v;
}

// ---------------- 128x128 bf16 NT GEMM core (y = x @ W^T + b) ----------------
// A: [M][1024] bf16 row-major, Bw: [N][1024] bf16 row-major (N = output feature)
// omode 0: bf16 out -> [b][h][s][64]; 1: fp32 row-major [m][1024]; 2: bf16 -> [b][h][64][s]
DEVINL void gemm_core(const ushort* __restrict__ A, const ushort* __restrict__ Bw,
                      const float* __restrict__ bias, void* __restrict__ Cout,
                      float scale, int omode, int row0, int col0)
{
  constexpr int K = 1024;
  __shared__ ushort As[128 * 64];
  __shared__ ushort Bs[128 * 64];
  const int t = threadIdx.x;
  const int l = t & 63;
  const int w = t >> 6;
  const int wr = w >> 1, wc = w & 1;

  // staging map: per issue i, thread covers row = t/8 + i*32, elem col = (t&7)*8
  const int srow = t >> 3;
  const int scol8 = (t & 7) * 8;
  const int swz_half = ((((t & 7) * 16) ^ ((srow & 7) << 4)) >> 1);  // ushort offset within 128B row

  const ushort* Ap = A + (size_t)(row0 + srow) * K + scol8;
  const ushort* Bp = Bw + (size_t)(col0 + srow) * K + scol8;

  bf16x8 areg[4], breg[4];
  auto loadstage = [&](int k0) {
#pragma unroll
    for (int i = 0; i < 4; ++i) {
      areg[i] = *(const bf16x8*)(Ap + (size_t)(i * 32) * K + k0);
      breg[i] = *(const bf16x8*)(Bp + (size_t)(i * 32) * K + k0);
    }
  };

  f32x4 acc[4][4];
#pragma unroll
  for (int i = 0; i < 4; ++i)
#pragma unroll
    for (int j = 0; j < 4; ++j) acc[i][j] = (f32x4){0.f, 0.f, 0.f, 0.f};

  loadstage(0);
#pragma unroll 1
  for (int kt = 0; kt < K / 64; ++kt) {
    __syncthreads();
#pragma unroll
    for (int i = 0; i < 4; ++i) {
      *(bf16x8*)&As[(srow + i * 32) * 64 + swz_half] = areg[i];
      *(bf16x8*)&Bs[(srow + i * 32) * 64 + swz_half] = breg[i];
    }
    if (kt + 1 < K / 64) loadstage((kt + 1) * 64);
    __syncthreads();
#pragma unroll
    for (int ks = 0; ks < 2; ++ks) {
      bf16x8 af[4], bfr[4];
#pragma unroll
      for (int mi = 0; mi < 4; ++mi) {
        int r = wr * 64 + mi * 16 + (l & 15);
        int cb = ((ks << 6) | ((l >> 4) << 4)) ^ ((r & 7) << 4);
        af[mi] = *(const bf16x8*)&As[r * 64 + (cb >> 1)];
      }
#pragma unroll
      for (int nj = 0; nj < 4; ++nj) {
        int r = wc * 64 + nj * 16 + (l & 15);
        int cb = ((ks << 6) | ((l >> 4) << 4)) ^ ((r & 7) << 4);
        bfr[nj] = *(const bf16x8*)&Bs[r * 64 + (cb >> 1)];
      }
#pragma unroll
      for (int mi = 0; mi < 4; ++mi)
#pragma unroll
        for (int nj = 0; nj < 4; ++nj)
          acc[mi][nj] = __builtin_amdgcn_mfma_f32_16x16x32_bf16(af[mi], bfr[nj], acc[mi][nj], 0, 0, 0);
    }
  }

  // epilogue: D layout col = lane&15, row = (lane>>4)*4 + reg
  const int cl = l & 15;
#pragma unroll
  for (int mi = 0; mi < 4; ++mi) {
#pragma unroll
    for (int nj = 0; nj < 4; ++nj) {
      int n = col0 + wc * 64 + nj * 16 + cl;
      float bv = bias[n];
      int mbase = row0 + wr * 64 + mi * 16 + (l >> 4) * 4;
      if (omode == 1) {
        float* Of = (float*)Cout;
#pragma unroll
        for (int ri = 0; ri < 4; ++ri)
          Of[(size_t)(mbase + ri) * 1024 + n] = (acc[mi][nj][ri] + bv) * scale;
      } else if (omode == 0) {
        ushort* Ob = (ushort*)Cout;
        int h = n >> 6, d = n & 63;
#pragma unroll
        for (int ri = 0; ri < 4; ++ri) {
          int m = mbase + ri;
          int b = m >> 11, s = m & 2047;
          Ob[(size_t)((b * 16 + h) * 2048 + s) * 64 + d] = f2bf((acc[mi][nj][ri] + bv) * scale);
        }
      } else {  // omode 2: transposed V layout [b][h][d][s]
        ushort* Ob = (ushort*)Cout;
        int h = n >> 6, d = n & 63;
        int b = mbase >> 11, s = mbase & 2047;
        union { u16x4 v; ushort u[4]; } pk;
#pragma unroll
        for (int ri = 0; ri < 4; ++ri) pk.u[ri] = f2bf((acc[mi][nj][ri] + bv) * scale);
        *(u16x4*)&Ob[(size_t)((b * 16 + h) * 64 + d) * 2048 + s] = pk.v;
      }
    }
  }
}

// fused QKV projection: blockIdx.z selects q/k/v
__global__ __launch_bounds__(256, 2) void gemm_qkv(
    const ushort* __restrict__ ws_c, ushort* __restrict__ ws_m,
    const float* __restrict__ bq, const float* __restrict__ bk, const float* __restrict__ bv)
{
  const int z = blockIdx.z;
  const ushort* A = ws_c + XQ_O + (size_t)z * 4194304;
  const ushort* W = ws_c + WQ_O + (size_t)z * 1048576;
  const float* bias = (z == 0) ? bq : ((z == 1) ? bk : bv);
  ushort* dst = ws_m + QB_O + (size_t)z * 4194304;
  float scale = (z == 0) ? 0.125f : 1.0f;  // fold 1/sqrt(dk) into Q
  int omode = (z == 2) ? 2 : 0;
  gemm_core(A, W, bias, dst, scale, omode, blockIdx.y * 128, blockIdx.x * 128);
}

__global__ __launch_bounds__(256, 2) void gemm_out(
    const ushort* __restrict__ ctx, const ushort* __restrict__ wo,
    const float* __restrict__ bo, float* __restrict__ out)
{
  gemm_core(ctx, wo, bo, out, 1.0f, 1, blockIdx.y * 128, blockIdx.x * 128);
}

// ---------------- flash attention ----------------
// grid: (qtile 0..15, bh 0..31), 256 threads = 4 waves; wave owns 32 q rows.
__global__ __launch_bounds__(256, 2) void attn128(
    const ushort* __restrict__ Qb, const ushort* __restrict__ Kb,
    const ushort* __restrict__ Vtb, ushort* __restrict__ Ctx)
{
  __shared__ ushort Ks[128 * 64];      // [kv][dk] swizzled, 128B rows
  __shared__ ushort Vs[64 * 128];      // [d][kv]  swizzled, 256B rows
  __shared__ ushort Ps[4][32 * 128];   // per-wave P [q][kv] swizzled, 256B rows

  const int t = threadIdx.x, l = t & 63, w = t >> 6;
  const int bh = blockIdx.y, qt = blockIdx.x;
  const ushort* Qp = Qb + ((size_t)bh * 2048 + qt * 128 + w * 32) * 64;
  const ushort* Kp = Kb + (size_t)bh * 2048 * 64;
  const ushort* Vp = Vtb + (size_t)bh * 64 * 2048;

  // Q fragments in registers (already scaled by 1/8)
  bf16x8 qf[2][2];
#pragma unroll
  for (int mi = 0; mi < 2; ++mi)
#pragma unroll
    for (int ks = 0; ks < 2; ++ks)
      qf[mi][ks] = *(const bf16x8*)(Qp + (mi * 16 + (l & 15)) * 64 + ks * 32 + ((l >> 4) << 3));

  const int krow = t >> 3;  const int kc8 = (t & 7) * 8;
  const int kswz = ((((t & 7) * 16) ^ ((krow & 7) << 4)) >> 1);
  const int vrow = t >> 4;  const int vc8 = (t & 15) * 8;
  const int vswz = ((((t & 15) * 16) ^ ((vrow & 7) << 4)) >> 1);

  bf16x8 kreg[4], vreg[4];
  auto loadKV = [&](int kv0) {
#pragma unroll
    for (int i = 0; i < 4; ++i) {
      kreg[i] = *(const bf16x8*)(Kp + (size_t)(kv0 + krow + i * 32) * 64 + kc8);
      vreg[i] = *(const bf16x8*)(Vp + (size_t)(vrow + i * 16) * 2048 + kv0 + vc8);
    }
  };

  f32x4 acc[2][4];
  float mrun[2][4], lrun[2][4];
#pragma unroll
  for (int mi = 0; mi < 2; ++mi) {
#pragma unroll
    for (int dj = 0; dj < 4; ++dj) acc[mi][dj] = (f32x4){0.f, 0.f, 0.f, 0.f};
#pragma unroll
    for (int ri = 0; ri < 4; ++ri) { mrun[mi][ri] = -1e30f; lrun[mi][ri] = 0.f; }
  }

  loadKV(0);
#pragma unroll 1
  for (int kt = 0; kt < 16; ++kt) {
    __syncthreads();
#pragma unroll
    for (int i = 0; i < 4; ++i) {
      *(bf16x8*)&Ks[(krow + i * 32) * 64 + kswz] = kreg[i];
      *(bf16x8*)&Vs[(vrow + i * 16) * 128 + vswz] = vreg[i];
    }
    if (kt + 1 < 16) loadKV((kt + 1) * 128);
    __syncthreads();

    // ---- S = Q K^T (scaled) ----
    f32x4 sfr[2][8];
#pragma unroll
    for (int kj = 0; kj < 8; ++kj) {
      int r = kj * 16 + (l & 15);
      int cb0 = (((l >> 4) << 4)) ^ ((r & 7) << 4);
      int cb1 = (64 | ((l >> 4) << 4)) ^ ((r & 7) << 4);
      bf16x8 kf0 = *(const bf16x8*)&Ks[r * 64 + (cb0 >> 1)];
      bf16x8 kf1 = *(const bf16x8*)&Ks[r * 64 + (cb1 >> 1)];
#pragma unroll
      for (int mi = 0; mi < 2; ++mi) {
        f32x4 z = (f32x4){0.f, 0.f, 0.f, 0.f};
        z = __builtin_amdgcn_mfma_f32_16x16x32_bf16(qf[mi][0], kf0, z, 0, 0, 0);
        sfr[mi][kj] = __builtin_amdgcn_mfma_f32_16x16x32_bf16(qf[mi][1], kf1, z, 0, 0, 0);
      }
    }

    // ---- online softmax + stage P to LDS (bf16) ----
#pragma unroll
    for (int mi = 0; mi < 2; ++mi) {
      float mnew[4], fsc[4];
#pragma unroll
      for (int ri = 0; ri < 4; ++ri) {
        float tm = sfr[mi][0][ri];
#pragma unroll
        for (int kj = 1; kj < 8; ++kj) tm = fmaxf(tm, sfr[mi][kj][ri]);
#pragma unroll
        for (int dd = 1; dd < 16; dd <<= 1) tm = fmaxf(tm, __shfl_xor(tm, dd));
        float mn = fmaxf(mrun[mi][ri], tm);
        fsc[ri] = __expf(mrun[mi][ri] - mn);
        mrun[mi][ri] = mn;
        mnew[ri] = mn;
        lrun[mi][ri] *= fsc[ri];
      }
#pragma unroll
      for (int dj = 0; dj < 4; ++dj)
#pragma unroll
        for (int ri = 0; ri < 4; ++ri) acc[mi][dj][ri] *= fsc[ri];
#pragma unroll
      for (int kj = 0; kj < 8; ++kj) {
#pragma unroll
        for (int ri = 0; ri < 4; ++ri) {
          float p = __expf(sfr[mi][kj][ri] - mnew[ri]);
          lrun[mi][ri] += p;
          int qr = mi * 16 + (l >> 4) * 4 + ri;
          int cb = (kj * 32 + ((l & 15) << 1)) ^ ((qr & 7) << 4);
          Ps[w][qr * 128 + (cb >> 1)] = f2bf(p);
        }
      }
    }

    // ---- O += P V ----
#pragma unroll
    for (int ks = 0; ks < 4; ++ks) {
      int cbb = (ks << 6) | ((l >> 4) << 4);
      bf16x8 pf[2], vf[4];
#pragma unroll
      for (int mi = 0; mi < 2; ++mi) {
        int r = mi * 16 + (l & 15);
        int cb = cbb ^ ((r & 7) << 4);
        pf[mi] = *(const bf16x8*)&Ps[w][r * 128 + (cb >> 1)];
      }
#pragma unroll
      for (int dj = 0; dj < 4; ++dj) {
        int d = dj * 16 + (l & 15);
        int cb = cbb ^ ((d & 7) << 4);
        vf[dj] = *(const bf16x8*)&Vs[d * 128 + (cb >> 1)];
      }
#pragma unroll
      for (int mi = 0; mi < 2; ++mi)
#pragma unroll
        for (int dj = 0; dj < 4; ++dj)
          acc[mi][dj] = __builtin_amdgcn_mfma_f32_16x16x32_bf16(pf[mi], vf[dj], acc[mi][dj], 0, 0, 0);
    }
  }

  // ---- finalize: divide by row sum, write ctx [b][s][1024] ----
  const int b = bh >> 4, h = bh & 15;
#pragma unroll
  for (int mi = 0; mi < 2; ++mi) {
    float inv[4];
#pragma unroll
    for (int ri = 0; ri < 4; ++ri) {
      float lsum = lrun[mi][ri];
#pragma unroll
      for (int dd = 1; dd < 16; dd <<= 1) lsum += __shfl_xor(lsum, dd);
      inv[ri] = 1.0f / lsum;
    }
#pragma unroll
    for (int dj = 0; dj < 4; ++dj) {
      int col = h * 64 + dj * 16 + (l & 15);
#pragma unroll
      for (int ri = 0; ri < 4; ++ri) {
        int s = qt * 128 + w * 32 + mi * 16 + (l >> 4) * 4 + ri;
        Ctx[((size_t)b * 2048 + s) * 1024 + col] = f2bf(acc[mi][dj][ri] * inv[ri]);
      }
    }
  }
}

extern "C" void kernel_launch(void* const* d_in, const int* in_sizes, int n_in,
                              void* d_out, int out_size, void* d_ws, size_t ws_size,
                              hipStream_t stream) {
  const float* xq = (const float*)d_in[0];
  const float* xk = (const float*)d_in[1];
  const float* xv = (const float*)d_in[2];
  const float* wq = (const float*)d_in[3];
  const float* bq = (const float*)d_in[4];
  const float* wk = (const float*)d_in[5];
  const float* bk = (const float*)d_in[6];
  const float* wv = (const float*)d_in[7];
  const float* bv = (const float*)d_in[8];
  const float* wo = (const float*)d_in[9];
  const float* bo = (const float*)d_in[10];
  ushort* ws = (ushort*)d_ws;

  cvt_all<<<8192, 256, 0, stream>>>(xq, xk, xv, wq, wk, wv, wo, ws);
  gemm_qkv<<<dim3(8, 32, 3), 256, 0, stream>>>(ws, ws, bq, bk, bv);
  attn128<<<dim3(16, 32), 256, 0, stream>>>(ws + QB_O, ws + KB_O, ws + VT_O, ws + CTX_O);
  gemm_out<<<dim3(8, 32), 256, 0, stream>>>(ws + CTX_O, ws + WO_O, bo, (float*)d_out);
}

// Round 2
// 140.967 us; speedup vs baseline: 1.0491x; 1.0491x over previous
//
#include <hip/hip_runtime.h>
#include <hip/hip_bf16.h>

using ushort = unsigned short;

typedef __attribute__((ext_vector_type(8))) short bf16x8;
typedef __attribute__((ext_vector_type(4))) short bf16x4;
typedef __attribute__((ext_vector_type(4))) float f32x4;
typedef __attribute__((ext_vector_type(4))) unsigned short u16x4;

#define DEVINL __device__ __forceinline__

// ---- problem constants ----
// B=2, S=2048, D=1024, H=16, dk=64, M=B*S=4096

// workspace layout (ushort element offsets)
static constexpr size_t XQ_O = 0;              // 4M elems (bf16 of query_tensor) -- reused as CTX later
static constexpr size_t XK_O = 4194304;
static constexpr size_t XV_O = 8388608;
static constexpr size_t WQ_O = 12582912;       // 1M each
static constexpr size_t WK_O = 13631488;
static constexpr size_t WV_O = 14680064;
static constexpr size_t WO_O = 15728640;
static constexpr size_t QB_O = 16777216;       // Q [b][h][s][64]   4M  (scaled by log2e/8)
static constexpr size_t KB_O = 20971520;       // K [b][h][s][64]   4M
static constexpr size_t VT_O = 25165824;       // V^T [b][h][64][s] 4M
static constexpr size_t CTX_O = 0;             // ctx [b][s][1024] reuses XQ

DEVINL ushort f2bf(float f) {
  unsigned u = __builtin_bit_cast(unsigned, f);
  u += 0x7fffu + ((u >> 16) & 1u);   // RNE
  return (ushort)(u >> 16);
}

DEVINL ushort f2bf_hw(float f) {
  __hip_bfloat16 h = __float2bfloat16(f);   // compiler emits v_cvt_pk_bf16_f32 for pairs (m240)
  return *reinterpret_cast<ushort*>(&h);
}

// ---------------- fp32 -> bf16 conversion of all inputs ----------------
__global__ __launch_bounds__(256) void cvt_all(
    const float* __restrict__ xq, const float* __restrict__ xk, const float* __restrict__ xv,
    const float* __restrict__ wq, const float* __restrict__ wk, const float* __restrict__ wv,
    const float* __restrict__ wo, ushort* __restrict__ ws)
{
  int e = (blockIdx.x * 256 + threadIdx.x) * 8;   // 16M elems total
  const float* s;
  if      (e < 4194304)  s = xq + e;
  else if (e < 8388608)  s = xk + (e - 4194304);
  else if (e < 12582912) s = xv + (e - 8388608);
  else if (e < 13631488) s = wq + (e - 12582912);
  else if (e < 14680064) s = wk + (e - 13631488);
  else if (e < 15728640) s = wv + (e - 14680064);
  else                   s = wo + (e - 15728640);
  float4 a = *(const float4*)s;
  float4 b = *(const float4*)(s + 4);
  union { u16x4 v; ushort u[4]; } r0, r1;
  r0.u[0] = f2bf(a.x); r0.u[1] = f2bf(a.y); r0.u[2] = f2bf(a.z); r0.u[3] = f2bf(a.w);
  r1.u[0] = f2bf(b.x); r1.u[1] = f2bf(b.y); r1.u[2] = f2bf(b.z); r1.u[3] = f2bf(b.w);
  *(u16x4*)(ws + e) = r0.v;
  *(u16x4*)(ws + e + 4) = r1.v;
}

// ---------------- 128x128 bf16 NT GEMM core (y = x @ W^T + b) ----------------
// A: [M][1024] bf16 row-major, Bw: [N][1024] bf16 row-major (N = output feature)
// omode 0: bf16 out -> [b][h][s][64]; 1: fp32 row-major [m][1024]; 2: bf16 -> [b][h][64][s]
DEVINL void gemm_core(const ushort* __restrict__ A, const ushort* __restrict__ Bw,
                      const float* __restrict__ bias, void* __restrict__ Cout,
                      float scale, int omode, int row0, int col0)
{
  constexpr int K = 1024;
  __shared__ ushort As[128 * 64];
  __shared__ ushort Bs[128 * 64];
  const int t = threadIdx.x;
  const int l = t & 63;
  const int w = t >> 6;
  const int wr = w >> 1, wc = w & 1;

  const int srow = t >> 3;
  const int scol8 = (t & 7) * 8;
  const int swz_half = ((((t & 7) * 16) ^ ((srow & 7) << 4)) >> 1);

  const ushort* Ap = A + (size_t)(row0 + srow) * K + scol8;
  const ushort* Bp = Bw + (size_t)(col0 + srow) * K + scol8;

  bf16x8 areg[4], breg[4];
  auto loadstage = [&](int k0) {
#pragma unroll
    for (int i = 0; i < 4; ++i) {
      areg[i] = *(const bf16x8*)(Ap + (size_t)(i * 32) * K + k0);
      breg[i] = *(const bf16x8*)(Bp + (size_t)(i * 32) * K + k0);
    }
  };

  f32x4 acc[4][4];
#pragma unroll
  for (int i = 0; i < 4; ++i)
#pragma unroll
    for (int j = 0; j < 4; ++j) acc[i][j] = (f32x4){0.f, 0.f, 0.f, 0.f};

  loadstage(0);
#pragma unroll 1
  for (int kt = 0; kt < K / 64; ++kt) {
    __syncthreads();
#pragma unroll
    for (int i = 0; i < 4; ++i) {
      *(bf16x8*)&As[(srow + i * 32) * 64 + swz_half] = areg[i];
      *(bf16x8*)&Bs[(srow + i * 32) * 64 + swz_half] = breg[i];
    }
    if (kt + 1 < K / 64) loadstage((kt + 1) * 64);
    __syncthreads();
#pragma unroll
    for (int ks = 0; ks < 2; ++ks) {
      bf16x8 af[4], bfr[4];
#pragma unroll
      for (int mi = 0; mi < 4; ++mi) {
        int r = wr * 64 + mi * 16 + (l & 15);
        int cb = ((ks << 6) | ((l >> 4) << 4)) ^ ((r & 7) << 4);
        af[mi] = *(const bf16x8*)&As[r * 64 + (cb >> 1)];
      }
#pragma unroll
      for (int nj = 0; nj < 4; ++nj) {
        int r = wc * 64 + nj * 16 + (l & 15);
        int cb = ((ks << 6) | ((l >> 4) << 4)) ^ ((r & 7) << 4);
        bfr[nj] = *(const bf16x8*)&Bs[r * 64 + (cb >> 1)];
      }
#pragma unroll
      for (int mi = 0; mi < 4; ++mi)
#pragma unroll
        for (int nj = 0; nj < 4; ++nj)
          acc[mi][nj] = __builtin_amdgcn_mfma_f32_16x16x32_bf16(af[mi], bfr[nj], acc[mi][nj], 0, 0, 0);
    }
  }

  // epilogue: D layout col = lane&15, row = (lane>>4)*4 + reg
  const int cl = l & 15;
#pragma unroll
  for (int mi = 0; mi < 4; ++mi) {
#pragma unroll
    for (int nj = 0; nj < 4; ++nj) {
      int n = col0 + wc * 64 + nj * 16 + cl;
      float bv = bias[n];
      int mbase = row0 + wr * 64 + mi * 16 + (l >> 4) * 4;
      if (omode == 1) {
        float* Of = (float*)Cout;
#pragma unroll
        for (int ri = 0; ri < 4; ++ri)
          Of[(size_t)(mbase + ri) * 1024 + n] = (acc[mi][nj][ri] + bv) * scale;
      } else if (omode == 0) {
        ushort* Ob = (ushort*)Cout;
        int h = n >> 6, d = n & 63;
#pragma unroll
        for (int ri = 0; ri < 4; ++ri) {
          int m = mbase + ri;
          int b = m >> 11, s = m & 2047;
          Ob[(size_t)((b * 16 + h) * 2048 + s) * 64 + d] = f2bf((acc[mi][nj][ri] + bv) * scale);
        }
      } else {  // omode 2: transposed V layout [b][h][d][s]
        ushort* Ob = (ushort*)Cout;
        int h = n >> 6, d = n & 63;
        int b = mbase >> 11, s = mbase & 2047;
        union { u16x4 v; ushort u[4]; } pk;
#pragma unroll
        for (int ri = 0; ri < 4; ++ri) pk.u[ri] = f2bf((acc[mi][nj][ri] + bv) * scale);
        *(u16x4*)&Ob[(size_t)((b * 16 + h) * 64 + d) * 2048 + s] = pk.v;
      }
    }
  }
}

// fused QKV projection: blockIdx.z selects q/k/v
__global__ __launch_bounds__(256, 2) void gemm_qkv(
    const ushort* __restrict__ ws_c, ushort* __restrict__ ws_m,
    const float* __restrict__ bq, const float* __restrict__ bk, const float* __restrict__ bv)
{
  const int z = blockIdx.z;
  const ushort* A = ws_c + XQ_O + (size_t)z * 4194304;
  const ushort* W = ws_c + WQ_O + (size_t)z * 1048576;
  const float* bias = (z == 0) ? bq : ((z == 1) ? bk : bv);
  ushort* dst = ws_m + QB_O + (size_t)z * 4194304;
  // fold 1/sqrt(dk) AND log2(e) into Q so softmax uses exp2 directly
  float scale = (z == 0) ? (0.125f * 1.4426950408889634f) : 1.0f;
  int omode = (z == 2) ? 2 : 0;
  gemm_core(A, W, bias, dst, scale, omode, blockIdx.y * 128, blockIdx.x * 128);
}

__global__ __launch_bounds__(256, 2) void gemm_out(
    const ushort* __restrict__ ctx, const ushort* __restrict__ wo,
    const float* __restrict__ bo, float* __restrict__ out)
{
  gemm_core(ctx, wo, bo, out, 1.0f, 1, blockIdx.y * 128, blockIdx.x * 128);
}

// ---------------- flash attention (swapped-QK^T, in-register softmax) ----------------
// grid: (qtile 0..15, bh 0..31), 256 threads = 4 waves; wave owns 32 q rows.
// S^T = mfma(K, Q): lane holds P^T[kv = kj*16+hi*4+ri][q = lane&15].
// PV uses a permuted contraction order: MFMA k-slot (hi,j) := kv 32*ks+16*(j>>2)+hi*4+(j&3),
// making the P^T B-fragment register-local and the V^T A-fragment two ds_read_b64.
__global__ __launch_bounds__(256, 2) void attn128(
    const ushort* __restrict__ Qb, const ushort* __restrict__ Kb,
    const ushort* __restrict__ Vtb, ushort* __restrict__ Ctx)
{
  __shared__ ushort Ks[128 * 64];      // [kv][dk] swizzled, 128B rows
  __shared__ ushort Vs[64 * 128];      // [d][kv]  swizzled, 256B rows

  const int t = threadIdx.x, l = t & 63, w = t >> 6;
  const int hi = l >> 4, q = l & 15;
  const int bh = blockIdx.y, qt = blockIdx.x;
  const ushort* Qp = Qb + ((size_t)bh * 2048 + qt * 128 + w * 32) * 64;
  const ushort* Kp = Kb + (size_t)bh * 2048 * 64;
  const ushort* Vp = Vtb + (size_t)bh * 64 * 2048;

  // Q fragments (B-operand): lane l -> col q=l&15, k-slice d = ks*32 + hi*8 + j
  bf16x8 qf[2][2];
#pragma unroll
  for (int qg = 0; qg < 2; ++qg)
#pragma unroll
    for (int ks = 0; ks < 2; ++ks)
      qf[qg][ks] = *(const bf16x8*)(Qp + (qg * 16 + q) * 64 + ks * 32 + hi * 8);

  const int krow = t >> 3;  const int kc8 = (t & 7) * 8;
  const int kswz = ((((t & 7) * 16) ^ ((krow & 7) << 4)) >> 1);
  const int vrow = t >> 4;  const int vc8 = (t & 15) * 8;
  const int vswz = ((((t & 15) * 16) ^ ((vrow & 7) << 4)) >> 1);

  bf16x8 kreg[4], vreg[4];
  auto loadKV = [&](int kv0) {
#pragma unroll
    for (int i = 0; i < 4; ++i) {
      kreg[i] = *(const bf16x8*)(Kp + (size_t)(kv0 + krow + i * 32) * 64 + kc8);
      vreg[i] = *(const bf16x8*)(Vp + (size_t)(vrow + i * 16) * 2048 + kv0 + vc8);
    }
  };

  f32x4 acc[2][4];   // O^T: row d = dj*16+hi*4+ri, col q = lane&15
#pragma unroll
  for (int qg = 0; qg < 2; ++qg)
#pragma unroll
    for (int dj = 0; dj < 4; ++dj) acc[qg][dj] = (f32x4){0.f, 0.f, 0.f, 0.f};
  float mrun[2] = {-1e30f, -1e30f};
  float lrun[2] = {0.f, 0.f};

  loadKV(0);
#pragma unroll 1
  for (int kt = 0; kt < 16; ++kt) {
    __syncthreads();
#pragma unroll
    for (int i = 0; i < 4; ++i) {
      *(bf16x8*)&Ks[(krow + i * 32) * 64 + kswz] = kreg[i];
      *(bf16x8*)&Vs[(vrow + i * 16) * 128 + vswz] = vreg[i];
    }
    if (kt + 1 < 16) loadKV((kt + 1) * 128);
    __syncthreads();

    // ---- S^T = K Q^T (log2-domain scores; scale folded into Q) ----
    f32x4 sfr[2][8];
    __builtin_amdgcn_s_setprio(1);
#pragma unroll
    for (int kj = 0; kj < 8; ++kj) {
      int r = kj * 16 + q;
      int cb0 = ((hi << 4)) ^ ((r & 7) << 4);
      int cb1 = (64 + (hi << 4)) ^ ((r & 7) << 4);
      bf16x8 kf0 = *(const bf16x8*)&Ks[r * 64 + (cb0 >> 1)];
      bf16x8 kf1 = *(const bf16x8*)&Ks[r * 64 + (cb1 >> 1)];
#pragma unroll
      for (int qg = 0; qg < 2; ++qg) {
        f32x4 z = (f32x4){0.f, 0.f, 0.f, 0.f};
        z = __builtin_amdgcn_mfma_f32_16x16x32_bf16(kf0, qf[qg][0], z, 0, 0, 0);
        sfr[qg][kj] = __builtin_amdgcn_mfma_f32_16x16x32_bf16(kf1, qf[qg][1], z, 0, 0, 0);
      }
    }
    __builtin_amdgcn_s_setprio(0);

    // ---- online softmax, fully lane-local (reduction over 4 hi-lanes only) ----
#pragma unroll
    for (int qg = 0; qg < 2; ++qg) {
      float p0 = sfr[qg][0][0], p1 = sfr[qg][0][1], p2 = sfr[qg][0][2], p3 = sfr[qg][0][3];
#pragma unroll
      for (int kj = 1; kj < 8; ++kj) {
        p0 = fmaxf(p0, sfr[qg][kj][0]); p1 = fmaxf(p1, sfr[qg][kj][1]);
        p2 = fmaxf(p2, sfr[qg][kj][2]); p3 = fmaxf(p3, sfr[qg][kj][3]);
      }
      float tm = fmaxf(fmaxf(p0, p1), fmaxf(p2, p3));
      tm = fmaxf(tm, __shfl_xor(tm, 16));
      tm = fmaxf(tm, __shfl_xor(tm, 32));
      float mnew = fmaxf(mrun[qg], tm);
      float fsc = exp2f(mrun[qg] - mnew);
      mrun[qg] = mnew;
      float s0 = 0.f, s1 = 0.f, s2 = 0.f, s3 = 0.f;
#pragma unroll
      for (int kj = 0; kj < 8; ++kj) {
        float e0 = exp2f(sfr[qg][kj][0] - mnew); sfr[qg][kj][0] = e0; s0 += e0;
        float e1 = exp2f(sfr[qg][kj][1] - mnew); sfr[qg][kj][1] = e1; s1 += e1;
        float e2 = exp2f(sfr[qg][kj][2] - mnew); sfr[qg][kj][2] = e2; s2 += e2;
        float e3 = exp2f(sfr[qg][kj][3] - mnew); sfr[qg][kj][3] = e3; s3 += e3;
      }
      lrun[qg] = lrun[qg] * fsc + ((s0 + s1) + (s2 + s3));
#pragma unroll
      for (int dj = 0; dj < 4; ++dj) {
        acc[qg][dj][0] *= fsc; acc[qg][dj][1] *= fsc;
        acc[qg][dj][2] *= fsc; acc[qg][dj][3] *= fsc;
      }
    }

    // ---- O^T += V^T P^T (permuted contraction; P stays in registers) ----
    __builtin_amdgcn_s_setprio(1);
#pragma unroll
    for (int ks = 0; ks < 4; ++ks) {
      union VU { bf16x8 v; bf16x4 h[2]; } vf[4];
#pragma unroll
      for (int dj = 0; dj < 4; ++dj) {
        int d = dj * 16 + q;
#pragma unroll
        for (int jh = 0; jh < 2; ++jh) {
          int bb = (64 * ks + 32 * jh + hi * 8) ^ ((d & 7) << 4);
          vf[dj].h[jh] = *(const bf16x4*)&Vs[d * 128 + (bb >> 1)];
        }
      }
#pragma unroll
      for (int qg = 0; qg < 2; ++qg) {
        union PU { bf16x8 v; ushort u[8]; } pb;
#pragma unroll
        for (int j = 0; j < 8; ++j)
          pb.u[j] = f2bf_hw(sfr[qg][2 * ks + (j >> 2)][j & 3]);
#pragma unroll
        for (int dj = 0; dj < 4; ++dj)
          acc[qg][dj] = __builtin_amdgcn_mfma_f32_16x16x32_bf16(vf[dj].v, pb.v, acc[qg][dj], 0, 0, 0);
      }
    }
    __builtin_amdgcn_s_setprio(0);
  }

  // ---- finalize: divide by row sum, write ctx [b][s][1024] (8B packed stores) ----
  const int b = bh >> 4, h = bh & 15;
#pragma unroll
  for (int qg = 0; qg < 2; ++qg) {
    float ls = lrun[qg];
    ls += __shfl_xor(ls, 16);
    ls += __shfl_xor(ls, 32);
    float inv = 1.0f / ls;
    int sg = qt * 128 + w * 32 + qg * 16 + q;
    ushort* dst = Ctx + ((size_t)b * 2048 + sg) * 1024 + h * 64;
#pragma unroll
    for (int dj = 0; dj < 4; ++dj) {
      union { u16x4 v; ushort u[4]; } pk;
#pragma unroll
      for (int ri = 0; ri < 4; ++ri)
        pk.u[ri] = f2bf_hw(acc[qg][dj][ri] * inv);
      *(u16x4*)(dst + dj * 16 + hi * 4) = pk.v;
    }
  }
}

extern "C" void kernel_launch(void* const* d_in, const int* in_sizes, int n_in,
                              void* d_out, int out_size, void* d_ws, size_t ws_size,
                              hipStream_t stream) {
  const float* xq = (const float*)d_in[0];
  const float* xk = (const float*)d_in[1];
  const float* xv = (const float*)d_in[2];
  const float* wq = (const float*)d_in[3];
  const float* bq = (const float*)d_in[4];
  const float* wk = (const float*)d_in[5];
  const float* bk = (const float*)d_in[6];
  const float* wv = (const float*)d_in[7];
  const float* bv = (const float*)d_in[8];
  const float* wo = (const float*)d_in[9];
  const float* bo = (const float*)d_in[10];
  ushort* ws = (ushort*)d_ws;

  cvt_all<<<8192, 256, 0, stream>>>(xq, xk, xv, wq, wk, wv, wo, ws);
  gemm_qkv<<<dim3(8, 32, 3), 256, 0, stream>>>(ws, ws, bq, bk, bv);
  attn128<<<dim3(16, 32), 256, 0, stream>>>(ws + QB_O, ws + KB_O, ws + VT_O, ws + CTX_O);
  gemm_out<<<dim3(8, 32), 256, 0, stream>>>(ws + CTX_O, ws + WO_O, bo, (float*)d_out);
}